// Round 4
// baseline (126.283 us; speedup 1.0000x reference)
//
#include <hip/hip_runtime.h>
#include <hip/hip_bf16.h>
#include <stdint.h>

#define NN 128
#define DD 64
#define HH 128
#define QPAD 68   // qbuf row stride in dwords: 16B-aligned, conflict-free for b128

__device__ __forceinline__ float bflo(uint32_t u){ union{uint32_t u;float f;} c; c.u = u<<16; return c.f; }
__device__ __forceinline__ float bfhi(uint32_t u){ union{uint32_t u;float f;} c; c.u = u & 0xffff0000u; return c.f; }
__device__ __forceinline__ uint32_t packbf(float lo, float hi){
  __hip_bfloat16 a = __float2bfloat16(lo);
  __hip_bfloat16 b = __float2bfloat16(hi);
  uint16_t ua = *(uint16_t*)&a, ub = *(uint16_t*)&b;
  return (uint32_t)ua | ((uint32_t)ub<<16);
}

// packed-pair accumulate: A_xy += relu(p + q) * a2, componentwise (maps to v_pk_*)
__device__ __forceinline__ void acc4(uint32_t qd0, uint32_t qd1,
                                     float2 p0, float2 p1, float2 a2,
                                     float2& A00, float2& A01, float2& A10, float2& A11){
  float2 q0 = make_float2(bflo(qd0), bfhi(qd0));
  float2 q1 = make_float2(bflo(qd1), bfhi(qd1));
  A00.x += fmaxf(p0.x+q0.x,0.f)*a2.x; A00.y += fmaxf(p0.y+q0.y,0.f)*a2.y;
  A01.x += fmaxf(p0.x+q1.x,0.f)*a2.x; A01.y += fmaxf(p0.y+q1.y,0.f)*a2.y;
  A10.x += fmaxf(p1.x+q0.x,0.f)*a2.x; A10.y += fmaxf(p1.y+q0.y,0.f)*a2.y;
  A11.x += fmaxf(p1.x+q1.x,0.f)*a2.x; A11.y += fmaxf(p1.y+q1.y,0.f)*a2.y;
}

// K1: blocks 0..511: projections; blocks 512..640: M = W2@U1[64:], c0 = b2@U1[64:]+ub1
__global__ __launch_bounds__(128) void k1_proj(
    const float* __restrict__ x,
    const float* __restrict__ W1, const float* __restrict__ b1,
    const float* __restrict__ A1, const float* __restrict__ ab1,
    const float* __restrict__ W2, const float* __restrict__ b2,
    const float* __restrict__ U1, const float* __restrict__ ub1,
    float* __restrict__ Pm, float* __restrict__ Pa,
    uint32_t* __restrict__ Qmp, uint32_t* __restrict__ Qap,
    float* __restrict__ M, float* __restrict__ c0){
  const int bid = blockIdx.x;
  const int t = threadIdx.x;           // 0..127
  if(bid >= 512){
    int hb = bid - 512;                // 0..128
    if(hb < HH){
      float acc = 0.f;
      #pragma unroll 4
      for(int k=0;k<HH;k++) acc += W2[hb*HH+k] * U1[(DD+k)*HH+t];
      M[hb*HH+t] = acc;
    } else {
      float acc = ub1[t];
      #pragma unroll 4
      for(int k=0;k<HH;k++) acc += b2[k] * U1[(DD+k)*HH+t];
      c0[t] = acc;
    }
    return;
  }
  const int g = bid & 15, b = bid >> 4;
  const int jb = g*4;
  __shared__ float xs[8][64];     // rows: jb..jb+3, jb+64..jb+67
  __shared__ float qmS[8][128];
  __shared__ float qaS[8][128];
  {
    int r = t >> 4, d4 = (t & 15)*4;
    int gr = (r<4) ? (jb+r) : (jb + r - 4 + 64);
    *(float4*)&xs[r][d4] = *(const float4*)&x[(b*NN+gr)*DD + d4];
  }
  __syncthreads();
  float pm[8], qm[8], pa[8], qa[8];
  #pragma unroll
  for(int r=0;r<8;r++){ pm[r]=0.f;qm[r]=0.f;pa[r]=0.f;qa[r]=0.f; }
  for(int d0=0; d0<DD; d0+=4){
    float4 xr[8];
    #pragma unroll
    for(int r=0;r<8;r++) xr[r] = *(const float4*)&xs[r][d0];
    #pragma unroll
    for(int dd=0; dd<4; dd++){
      const int d = d0 + dd;
      float w1a = W1[d*HH + t];
      float w1b = W1[(DD+d)*HH + t];
      float a1a = A1[d*HH + t];
      float a1b = A1[(DD+d)*HH + t];
      #pragma unroll
      for(int r=0;r<8;r++){
        float xv = (&xr[r].x)[dd];
        pm[r] += xv*w1a; qm[r] += xv*w1b;
        pa[r] += xv*a1a; qa[r] += xv*a1b;
      }
    }
  }
  float b1v = b1[t], ab1v = ab1[t];
  #pragma unroll
  for(int r=0;r<8;r++){
    int gr = (r<4) ? (jb+r) : (jb + r - 4 + 64);
    Pm[(b*NN+gr)*HH + t] = pm[r] + b1v;
    Pa[(b*NN+gr)*HH + t] = pa[r] + ab1v;
    qmS[r][t] = qm[r];
    qaS[r][t] = qa[r];
  }
  __syncthreads();
  #pragma unroll
  for(int k=0;k<4;k++){
    int idx = t + k*128;              // 0..511
    int r = idx >> 6, hp = idx & 63;
    int gr = (r<4) ? (jb+r) : (jb + r - 4 + 64);
    Qmp[(b*NN+gr)*64 + hp] = packbf(qmS[r][hp], qmS[r][hp+64]);
    Qap[(b*NN+gr)*64 + hp] = packbf(qaS[r][hp], qaS[r][hp+64]);
  }
}

// K2 (fully fused): attn logits + masked softmax + weighted message agg + update MLP + residual.
// Block = (batch b, 8 i-rows). P arrays staged interleaved: pSi[r][2*h2+half] = P[r][h2+64*half],
// so (h, h+64) float2 pairs match the packed-bf16 Q dwords -> clean v_pk_* pairing.
__global__ __launch_bounds__(256) void k2_fused(
    const float* __restrict__ Pa, const float* __restrict__ Pm,
    const uint32_t* __restrict__ Qap, const uint32_t* __restrict__ Qmp,
    const float* __restrict__ A2, const int* __restrict__ masks,
    const float* __restrict__ M, const float* __restrict__ c0,
    const float* __restrict__ U1, const float* __restrict__ U2,
    const float* __restrict__ ub2, const float* __restrict__ x,
    float* __restrict__ out){
  const int it = blockIdx.x;     // 0..15 (8 i each)
  const int b  = blockIdx.y;     // 0..31
  const int t = threadIdx.x;     // 0..255
  const int wave = t>>6, lane = t&63;
  __shared__ uint32_t qbuf[NN*QPAD]; // 34.8 KB
  __shared__ float pSi[8*HH];        // interleaved P pairs
  __shared__ float a2i[HH];          // interleaved A2 pairs
  __shared__ float atS[8*NN];        // attention weights
  __shared__ float hbS[8*HH];        // aggregated messages
  __shared__ float hidS[8*HH];       // update-net hidden
  __shared__ float xs[8][64];
  __shared__ float c0S[HH];
  const int i0 = wave*2, i1 = i0+1;
  const int row0 = b*NN + it*8;
  // ---- stage Qa, Pa(interleaved), A2(interleaved), x, c0 ----
  {
    const uint32_t* src = Qap + (size_t)b*NN*64;
    #pragma unroll
    for(int k=0;k<8;k++){
      int idx4 = t + k*256;                  // uint4 index 0..2047
      int j = idx4 >> 4, hp4 = (idx4 & 15)*4;
      *(uint4*)&qbuf[j*QPAD + hp4] = *(const uint4*)&src[j*64 + hp4];
    }
    #pragma unroll
    for(int k=0;k<4;k++){
      int idx = t + k*256;                   // 0..1023
      int r = idx>>7, rem = idx&127, h2 = rem&63, half = rem>>6;
      pSi[r*HH + 2*h2 + half] = Pa[(row0 + r)*HH + h2 + 64*half];
    }
    if(t < HH) a2i[2*(t&63) + (t>>6)] = A2[t];
    if(t < 128){ int r = t>>4, d4 = (t&15)*4;
      *(float4*)&xs[r][d4] = *(const float4*)&x[(row0 + r)*DD + d4]; }
    else { int u = t-128; if(u < HH) c0S[u] = c0[u]; }
  }
  const int m0 = masks[b*NN + lane];
  const int m1 = masks[b*NN + 64 + lane];
  __syncthreads();
  // ---- phase 1: logits + masked softmax ----
  {
    float2 A00=make_float2(0.f,0.f), A01=A00, A10=A00, A11=A00;
    for(int hp0=0; hp0<64; hp0+=4){
      uint4 q0 = *(const uint4*)&qbuf[lane*QPAD + hp0];
      uint4 q1 = *(const uint4*)&qbuf[(lane+64)*QPAD + hp0];
      float4 p0a = *(const float4*)&pSi[i0*HH + 2*hp0];
      float4 p0b = *(const float4*)&pSi[i0*HH + 2*hp0 + 4];
      float4 p1a = *(const float4*)&pSi[i1*HH + 2*hp0];
      float4 p1b = *(const float4*)&pSi[i1*HH + 2*hp0 + 4];
      float4 aa  = *(const float4*)&a2i[2*hp0];
      float4 ab  = *(const float4*)&a2i[2*hp0 + 4];
      acc4(q0.x, q1.x, make_float2(p0a.x,p0a.y), make_float2(p1a.x,p1a.y),
           make_float2(aa.x,aa.y), A00,A01,A10,A11);
      acc4(q0.y, q1.y, make_float2(p0a.z,p0a.w), make_float2(p1a.z,p1a.w),
           make_float2(aa.z,aa.w), A00,A01,A10,A11);
      acc4(q0.z, q1.z, make_float2(p0b.x,p0b.y), make_float2(p1b.x,p1b.y),
           make_float2(ab.x,ab.y), A00,A01,A10,A11);
      acc4(q0.w, q1.w, make_float2(p0b.z,p0b.w), make_float2(p1b.z,p1b.w),
           make_float2(ab.z,ab.w), A00,A01,A10,A11);
    }
    float l[2][2] = {{A00.x+A00.y, A01.x+A01.y},{A10.x+A10.y, A11.x+A11.y}};
    const float NEG = -3.0e38f;
    #pragma unroll
    for(int ii=0; ii<2; ii++){
      float x0 = l[ii][0], x1 = l[ii][1];
      int il = i0 + ii;
      float v = fmaxf(m0 ? x0 : NEG, m1 ? x1 : NEG);
      for(int off=32; off>=1; off>>=1) v = fmaxf(v, __shfl_xor(v, off));
      float e0 = m0 ? __expf(x0 - v) : 0.f;
      float e1 = m1 ? __expf(x1 - v) : 0.f;
      float s = e0 + e1;
      for(int off=32; off>=1; off>>=1) s += __shfl_xor(s, off);
      float inv = (s > 0.f) ? (1.f/s) : 0.f;
      atS[il*NN + lane]      = e0*inv;
      atS[il*NN + 64 + lane] = e1*inv;
    }
  }
  __syncthreads();   // phase-1 qbuf/pSi reads done; atS visible
  // ---- restage Qm, Pm(interleaved) ----
  {
    const uint32_t* src = Qmp + (size_t)b*NN*64;
    #pragma unroll
    for(int k=0;k<8;k++){
      int idx4 = t + k*256;
      int j = idx4 >> 4, hp4 = (idx4 & 15)*4;
      *(uint4*)&qbuf[j*QPAD + hp4] = *(const uint4*)&src[j*64 + hp4];
    }
    #pragma unroll
    for(int k=0;k<4;k++){
      int idx = t + k*256;
      int r = idx>>7, rem = idx&127, h2 = rem&63, half = rem>>6;
      pSi[r*HH + 2*h2 + half] = Pm[(row0 + r)*HH + h2 + 64*half];
    }
  }
  __syncthreads();
  // ---- phase 2: hbar = sum_j attn * relu(Pm + Qm) ----
  {
    float2 pm0 = *(const float2*)&pSi[i0*HH + 2*lane];
    float2 pm1 = *(const float2*)&pSi[i1*HH + 2*lane];
    float2 H0 = make_float2(0.f,0.f), H1 = H0;
    for(int j0=0; j0<NN; j0+=4){
      float4 at0 = *(const float4*)&atS[i0*NN + j0];
      float4 at1 = *(const float4*)&atS[i1*NN + j0];
      #pragma unroll
      for(int dd=0; dd<4; dd++){
        uint32_t qd = qbuf[(j0+dd)*QPAD + lane];
        float ql = bflo(qd), qh = bfhi(qd);
        float w0 = (&at0.x)[dd], w1 = (&at1.x)[dd];
        H0.x += w0*fmaxf(pm0.x+ql,0.f); H0.y += w0*fmaxf(pm0.y+qh,0.f);
        H1.x += w1*fmaxf(pm1.x+ql,0.f); H1.y += w1*fmaxf(pm1.y+qh,0.f);
      }
    }
    hbS[i0*HH + lane]      = H0.x;
    hbS[i0*HH + 64 + lane] = H0.y;
    hbS[i1*HH + lane]      = H1.x;
    hbS[i1*HH + 64 + lane] = H1.y;
  }
  __syncthreads();
  // ---- phase A: hidden = relu(x@U1[:64] + hbar@M + c0) ----
  {
    const int r = t>>5, c4 = (t&31)*4;
    float4 acc = *(const float4*)&c0S[c4];
    for(int d0=0; d0<DD; d0+=4){
      float4 xv4 = *(const float4*)&xs[r][d0];
      #pragma unroll
      for(int dd=0; dd<4; dd++){
        float4 u = *(const float4*)&U1[(d0+dd)*HH + c4];
        float xv = (&xv4.x)[dd];
        acc.x += xv*u.x; acc.y += xv*u.y; acc.z += xv*u.z; acc.w += xv*u.w;
      }
    }
    for(int h0=0; h0<HH; h0+=4){
      float4 hv4 = *(const float4*)&hbS[r*HH + h0];
      #pragma unroll
      for(int dd=0; dd<4; dd++){
        float4 m = *(const float4*)&M[(h0+dd)*HH + c4];
        float hv = (&hv4.x)[dd];
        acc.x += hv*m.x; acc.y += hv*m.y; acc.z += hv*m.z; acc.w += hv*m.w;
      }
    }
    float4 hid;
    hid.x = fmaxf(acc.x,0.f); hid.y = fmaxf(acc.y,0.f);
    hid.z = fmaxf(acc.z,0.f); hid.w = fmaxf(acc.w,0.f);
    *(float4*)&hidS[r*HH + c4] = hid;
  }
  __syncthreads();
  // ---- phase B: out = x + hidden@U2 + ub2 ----
  {
    const int r = t>>5, dc2 = (t&31)*2;
    float2 acc2 = make_float2(0.f,0.f);
    for(int ci=0; ci<HH; ci+=4){
      float4 hv4 = *(const float4*)&hidS[r*HH + ci];
      #pragma unroll
      for(int dd=0; dd<4; dd++){
        float2 u2 = *(const float2*)&U2[(ci+dd)*DD + dc2];
        float hv = (&hv4.x)[dd];
        acc2.x += hv*u2.x; acc2.y += hv*u2.y;
      }
    }
    float2 ub = *(const float2*)&ub2[dc2];
    float2 xv = *(const float2*)&xs[r][dc2];
    float2 o = make_float2(xv.x + acc2.x + ub.x, xv.y + acc2.y + ub.y);
    *(float2*)&out[(row0 + r)*DD + dc2] = o;
  }
}

extern "C" void kernel_launch(void* const* d_in, const int* in_sizes, int n_in,
                              void* d_out, int out_size, void* d_ws, size_t ws_size,
                              hipStream_t stream){
  const float* x   = (const float*)d_in[0];
  const int*   msk = (const int*)d_in[1];
  const float* W1  = (const float*)d_in[2];
  const float* b1  = (const float*)d_in[3];
  const float* W2  = (const float*)d_in[4];
  const float* b2  = (const float*)d_in[5];
  const float* A1  = (const float*)d_in[6];
  const float* ab1 = (const float*)d_in[7];
  const float* A2  = (const float*)d_in[8];
  // d_in[9] = ab2: softmax-invariant -> unused
  const float* U1  = (const float*)d_in[10];
  const float* ub1 = (const float*)d_in[11];
  const float* U2  = (const float*)d_in[12];
  const float* ub2 = (const float*)d_in[13];
  float* out = (float*)d_out;

  char* w = (char*)d_ws;
  float*    Pm   = (float*)(w);                        // 2 MB
  float*    Pa   = (float*)(w + (2u<<20));             // 2 MB
  uint32_t* Qmp  = (uint32_t*)(w + (4u<<20));          // 1 MB packed bf16 pairs
  uint32_t* Qap  = (uint32_t*)(w + (5u<<20));          // 1 MB
  float*    M    = (float*)(w + (6u<<20));             // 64 KB
  float*    c0   = (float*)(w + (6u<<20) + (64u<<10)); // 512 B

  hipLaunchKernelGGL(k1_proj, dim3(641), dim3(128), 0, stream,
                     x, W1, b1, A1, ab1, W2, b2, U1, ub1,
                     Pm, Pa, Qmp, Qap, M, c0);
  hipLaunchKernelGGL(k2_fused, dim3(16,32), dim3(256), 0, stream,
                     Pa, Pm, Qap, Qmp, A2, msk, M, c0, U1, U2, ub2, x, out);
}